// Round 1
// baseline (97.507 us; speedup 1.0000x reference)
//
#include <hip/hip_runtime.h>

// 3D spatial transformer (trilinear grid sample, zeros padding).
// src:  (1,1,160,192,224) f32
// flow: (1,3,160,192,224) f32   channel 0->d, 1->h, 2->w displacement
// out:  (1,1,160,192,224) f32

constexpr int Dd = 160;
constexpr int Hh = 192;
constexpr int Ww = 224;
constexpr int HW = Hh * Ww;          // 43008
constexpr int N  = Dd * HW;          // 6,881,280

__global__ __launch_bounds__(256)
void st3d_kernel(const float* __restrict__ src,
                 const float* __restrict__ flow,
                 float* __restrict__ out) {
    int i = blockIdx.x * 256 + threadIdx.x;
    if (i >= N) return;

    int w = i % Ww;
    int t = i / Ww;
    int h = t % Hh;
    int d = t / Hh;

    float cd = (float)d + flow[i];
    float ch = (float)h + flow[N + i];
    float cw = (float)w + flow[2 * N + i];

    float d0f = floorf(cd), h0f = floorf(ch), w0f = floorf(cw);
    float fd = cd - d0f, fh = ch - h0f, fw = cw - w0f;

    int d0 = (int)d0f, h0 = (int)h0f, w0 = (int)w0f;
    int d1 = d0 + 1, h1 = h0 + 1, w1 = w0 + 1;

    bool bd0 = (unsigned)d0 < (unsigned)Dd;
    bool bd1 = (unsigned)d1 < (unsigned)Dd;
    bool bh0 = (unsigned)h0 < (unsigned)Hh;
    bool bh1 = (unsigned)h1 < (unsigned)Hh;
    bool bw0 = (unsigned)w0 < (unsigned)Ww;
    bool bw1 = (unsigned)w1 < (unsigned)Ww;

    float wd1 = fd, wd0 = 1.0f - fd;
    float wh1 = fh, wh0 = 1.0f - fh;
    float ww1 = fw, ww0 = 1.0f - fw;

    // Predicated gather: only load when in-bounds (weight is exactly 0 otherwise,
    // matching the reference's inb mask).
    auto at = [&](int dd, int hh, int ww, bool ok) -> float {
        return ok ? src[(dd * Hh + hh) * Ww + ww] : 0.0f;
    };

    float v000 = at(d0, h0, w0, bd0 && bh0 && bw0);
    float v001 = at(d0, h0, w1, bd0 && bh0 && bw1);
    float v010 = at(d0, h1, w0, bd0 && bh1 && bw0);
    float v011 = at(d0, h1, w1, bd0 && bh1 && bw1);
    float v100 = at(d1, h0, w0, bd1 && bh0 && bw0);
    float v101 = at(d1, h0, w1, bd1 && bh0 && bw1);
    float v110 = at(d1, h1, w0, bd1 && bh1 && bw0);
    float v111 = at(d1, h1, w1, bd1 && bh1 && bw1);

    float acc =
        wd0 * (wh0 * (ww0 * v000 + ww1 * v001) +
               wh1 * (ww0 * v010 + ww1 * v011)) +
        wd1 * (wh0 * (ww0 * v100 + ww1 * v101) +
               wh1 * (ww0 * v110 + ww1 * v111));

    out[i] = acc;
}

extern "C" void kernel_launch(void* const* d_in, const int* in_sizes, int n_in,
                              void* d_out, int out_size, void* d_ws, size_t ws_size,
                              hipStream_t stream) {
    const float* src  = (const float*)d_in[0];
    const float* flow = (const float*)d_in[1];
    float* out = (float*)d_out;

    int blocks = (N + 255) / 256;  // 26880
    st3d_kernel<<<blocks, 256, 0, stream>>>(src, flow, out);
}